// Round 9
// baseline (448.169 us; speedup 1.0000x reference)
//
#include <hip/hip_runtime.h>
#include <math.h>

typedef _Float16 f16;
typedef _Float16 f16x2 __attribute__((ext_vector_type(2)));
typedef _Float16 f16x8 __attribute__((ext_vector_type(8)));
typedef _Float16 f16x4 __attribute__((ext_vector_type(4)));
typedef float f32x4 __attribute__((ext_vector_type(4)));

#define B_ 4
#define S_ 1024
#define H_ 1280
#define NH_ 20
#define DH_ 64
#define I_ 5120
#define C_ 13
#define P_ 8
#define QS_ 3840                      // fused QKV row stride
#define LOG2E 1.44269504088896f

__device__ __forceinline__ void store_val(float* p, float v) { *p = v; }
__device__ __forceinline__ void store_val(f16* p, float v) { *p = (f16)v; }

// Exact-GELU via Abramowitz-Stegun 7.1.26 erf (|eps| <= 1.5e-7; << f16 ulp).
__device__ __forceinline__ float fast_gelu(float x) {
    float ax = 0.70710678118654752f * fabsf(x);
    float t = __builtin_amdgcn_rcpf(1.0f + 0.3275911f * ax);
    float p = t * (0.254829592f + t * (-0.284496736f + t * (1.421413741f
              + t * (-1.453152027f + t * 1.061405429f))));
    float e = __builtin_exp2f(-(LOG2E) * ax * ax);
    float er = 1.0f - p * e;                       // erf(|x|/sqrt2)
    float cdf = 0.5f + 0.5f * (x >= 0.0f ? er : -er);
    return x * cdf;
}

// tanh via exp2 + rcp (~5e-7 abs err). Input clamped to +-20.
__device__ __forceinline__ float fast_tanh(float x) {
    x = fminf(fmaxf(x, -20.0f), 20.0f);
    float e = __builtin_exp2f(x * (2.0f * LOG2E));
    return (e - 1.0f) * __builtin_amdgcn_rcpf(e + 1.0f);
}

// ---------------------------------------------------------------------------
// prep_kernel: blocks 0..1023 = ptm (softmax(h@Wptm^T+b) and t = ptm@R, one
// wave per token row; also emits hin16). Blocks 1024.. = f32->f16 weight
// conversion (Wq/Wk/Wv: 1600 blocks each; Wf1/Wf2: 6400 each).
// ---------------------------------------------------------------------------
__global__ __launch_bounds__(256) void prep_kernel(const float* __restrict__ hin,
                                                   const float* __restrict__ Wptm,
                                                   const float* __restrict__ bptm,
                                                   const float* __restrict__ Mg,
                                                   const float* __restrict__ W1,
                                                   const float* __restrict__ b1,
                                                   const float* __restrict__ W2,
                                                   const float* __restrict__ b2,
                                                   float* __restrict__ ptm,
                                                   float* __restrict__ tg,
                                                   f16* __restrict__ hin16,
                                                   const float* __restrict__ Wq,
                                                   const float* __restrict__ Wk,
                                                   const float* __restrict__ Wv,
                                                   const float* __restrict__ Wf1,
                                                   const float* __restrict__ Wf2,
                                                   f16* __restrict__ Wq16,
                                                   f16* __restrict__ Wk16,
                                                   f16* __restrict__ Wv16,
                                                   f16* __restrict__ Wf116,
                                                   f16* __restrict__ Wf216) {
    const int bid = blockIdx.x;
    int t = threadIdx.x;
    if (bid >= 1024) {
        const int cb = bid - 1024;
        const float* src; f16* dst; int base;
        if (cb < 4800) {
            const int s = cb / 1600;
            src = (s == 0) ? Wq : (s == 1) ? Wk : Wv;
            dst = (s == 0) ? Wq16 : (s == 1) ? Wk16 : Wv16;
            base = (cb - s * 1600) * 256;
        } else if (cb < 11200) {
            src = Wf1; dst = Wf116; base = (cb - 4800) * 256;
        } else {
            src = Wf2; dst = Wf216; base = (cb - 11200) * 256;
        }
        const int i = base + t;
        f32x4 v = ((const f32x4*)src)[i];
        f16x4 o;
#pragma unroll
        for (int e = 0; e < 4; e++) o[e] = (f16)v[e];
        ((f16x4*)dst)[i] = o;
        return;
    }

    __shared__ float o1[P_][C_];
    __shared__ float o2[C_][P_];
    __shared__ float R[P_ * P_];
    if (t < P_ * C_) {
        int p = t / C_, c = t % C_;
        float s = b1[p];
        for (int k = 0; k < C_; k++) s += Mg[k * C_ + c] * W1[p * C_ + k];
        o1[p][c] = s;
        int c2 = t / P_, p2 = t % P_;
        float s2 = b2[p2];
        for (int k = 0; k < C_; k++) s2 += Mg[c2 * C_ + k] * W2[p2 * C_ + k];
        o2[c2][p2] = s2;
    }
    __syncthreads();
    if (t < P_ * P_) {
        int p = t >> 3, q = t & 7;
        float s = 0.f;
        for (int c = 0; c < C_; c++) s += o1[p][c] * o2[c][q];
        R[t] = s;
    }
    __syncthreads();

    int wv = t >> 6, lane = t & 63;
    int row = bid * 4 + wv;
    const float* hrow = hin + (size_t)row * H_;
    f16* hrow16 = hin16 + (size_t)row * H_;
    float acc[P_] = {};
    for (int i = 0; i < H_ / 64; i++) {
        int k = lane + 64 * i;
        float hv = hrow[k];
        hrow16[k] = (f16)hv;
#pragma unroll
        for (int p = 0; p < P_; p++) acc[p] += hv * Wptm[p * H_ + k];
    }
#pragma unroll
    for (int p = 0; p < P_; p++) {
#pragma unroll
        for (int o = 32; o >= 1; o >>= 1) acc[p] += __shfl_xor(acc[p], o);
        acc[p] += bptm[p];
    }
    float mx = acc[0];
#pragma unroll
    for (int p = 1; p < P_; p++) mx = fmaxf(mx, acc[p]);
    float sum = 0.f;
#pragma unroll
    for (int p = 0; p < P_; p++) { acc[p] = expf(acc[p] - mx); sum += acc[p]; }
    float rinv = 1.f / sum;
#pragma unroll
    for (int p = 0; p < P_; p++) acc[p] *= rinv;
    float tv[P_];
#pragma unroll
    for (int d = 0; d < P_; d++) {
        float s = 0.f;
#pragma unroll
        for (int c = 0; c < P_; c++) s += acc[c] * R[c * P_ + d];
        tv[d] = s;
    }
    if (lane == 0) {
#pragma unroll
        for (int p = 0; p < P_; p++) {
            ptm[(size_t)row * P_ + p] = acc[p];
            tg[(size_t)row * P_ + p]  = tv[p];
        }
    }
}

// ---------------------------------------------------------------------------
// Bias precompute, LOG2E-folded: bb = (tanh(dot8)*bscale + maskterm) * LOG2E
// ---------------------------------------------------------------------------
__global__ __launch_bounds__(256) void bias_kernel(const float* __restrict__ tg,
                                                   const float* __restrict__ ptm,
                                                   const float* __restrict__ mask,
                                                   const float* __restrict__ bscale_p,
                                                   f16* __restrict__ bb) {
    const int bl = blockIdx.x;          // b*1024 + l
    const int b = bl >> 10;
    const int t = threadIdx.x;
    __shared__ float tl[P_];
    if (t < P_) tl[t] = tg[(size_t)bl * P_ + t];
    __syncthreads();
    const float bscale = bscale_p[0];
    float t0 = tl[0], t1 = tl[1], t2 = tl[2], t3 = tl[3];
    float t4 = tl[4], t5 = tl[5], t6 = tl[6], t7 = tl[7];
#pragma unroll
    for (int i = 0; i < 4; i++) {
        int m = t + 256 * i;
        const float* pm = ptm + ((size_t)b * S_ + m) * P_;
        float4 p0 = *(const float4*)pm;
        float4 p1 = *(const float4*)(pm + 4);
        float d = t0 * p0.x + t1 * p0.y + t2 * p0.z + t3 * p0.w
                + t4 * p1.x + t5 * p1.y + t6 * p1.z + t7 * p1.w;
        float v = (fast_tanh(d) * bscale + (1.0f - mask[(size_t)b * S_ + m]) * (-30000.0f)) * LOG2E;
        bb[(size_t)bl * S_ + m] = (f16)v;
    }
}

// ---------------------------------------------------------------------------
// m97-style GEMM body: 128x128 tile, BK=64, global_load_lds width=16,
// XOR swizzle on the global-address side. 2 blocks/CU. (FFN1.)
// MODE 0: plain f16 out. MODE 1: fast exact GELU.
// ---------------------------------------------------------------------------
template <int MODE, typename YT>
__device__ __forceinline__ void gemm_body(const f16* __restrict__ X,
                                          const f16* __restrict__ W,
                                          const float* __restrict__ bias,
                                          YT* __restrict__ Y,
                                          int Ndim, int Kdim, int kbeg, int kend,
                                          int m0, int n0, f16* sA, f16* sB) {
    const int t = threadIdx.x;
    const int lane = t & 63, w = t >> 6;
    const int wr = w >> 1, wc = w & 1;
    const int lr = lane & 15, kq = lane >> 4;

    f32x4 acc[4][4] = {};

    int s_row[4], s_gc[4];
#pragma unroll
    for (int inst = 0; inst < 4; inst++) {
        int ci = t + 256 * inst;
        s_row[inst] = ci >> 3;
        s_gc[inst] = (ci & 7) ^ (s_row[inst] & 7);
    }

    for (int k0 = kbeg; k0 < kend; k0 += 64) {
        __syncthreads();
#pragma unroll
        for (int inst = 0; inst < 4; inst++) {
            int ci = t + 256 * inst;
            __builtin_amdgcn_global_load_lds(
                (const unsigned*)(X + (size_t)(m0 + s_row[inst]) * Kdim + k0 + s_gc[inst] * 8),
                (unsigned*)(sA + ci * 8), 16, 0, 0);
        }
#pragma unroll
        for (int inst = 0; inst < 4; inst++) {
            int ci = t + 256 * inst;
            __builtin_amdgcn_global_load_lds(
                (const unsigned*)(W + (size_t)(n0 + s_row[inst]) * Kdim + k0 + s_gc[inst] * 8),
                (unsigned*)(sB + ci * 8), 16, 0, 0);
        }
        __syncthreads();
#pragma unroll
        for (int ks = 0; ks < 2; ks++) {
            f16x8 af[4], bf[4];
#pragma unroll
            for (int i = 0; i < 4; i++) {
                int row = wr * 64 + i * 16 + lr;
                int cl = (ks * 4 + kq) ^ (row & 7);
                af[i] = *(const f16x8*)(sA + row * 64 + cl * 8);
            }
#pragma unroll
            for (int j = 0; j < 4; j++) {
                int row = wc * 64 + j * 16 + lr;
                int cl = (ks * 4 + kq) ^ (row & 7);
                bf[j] = *(const f16x8*)(sB + row * 64 + cl * 8);
            }
#pragma unroll
            for (int i = 0; i < 4; i++)
#pragma unroll
                for (int j = 0; j < 4; j++)
                    acc[i][j] = __builtin_amdgcn_mfma_f32_16x16x32_f16(af[i], bf[j], acc[i][j], 0, 0, 0);
        }
    }
#pragma unroll
    for (int j = 0; j < 4; j++) {
        int col = n0 + wc * 64 + j * 16 + lr;
        float bcol = bias[col];
#pragma unroll
        for (int i = 0; i < 4; i++) {
#pragma unroll
            for (int rr = 0; rr < 4; rr++) {
                int row = m0 + wr * 64 + i * 16 + kq * 4 + rr;
                float v = acc[i][j][rr] + bcol;
                if (MODE == 1) v = fast_gelu(v);
                store_val(&Y[(size_t)row * Ndim + col], v);
            }
        }
    }
}

template <int MODE, typename YT>
__global__ __launch_bounds__(256, 2) void gemm128(const f16* __restrict__ X,
                                                  const f16* __restrict__ W,
                                                  const float* __restrict__ bias,
                                                  YT* __restrict__ Y,
                                                  int Ndim, int Kdim) {
    __shared__ f16 sA[128 * 64];
    __shared__ f16 sB[128 * 64];
    gemm_body<MODE, YT>(X, W, bias, Y, Ndim, Kdim, 0, Kdim,
                        blockIdx.x * 128, blockIdx.y * 128, sA, sB);
}

// ---------------------------------------------------------------------------
// Deep-pipelined 256x256 GEMM body: 8 waves (2x4), BK=64, double-buffered
// LDS, counted vmcnt(8) per K-tile. (QKV + FFN2-sk.)
// MODE 0: bias + f16 out. MODE 3: raw partial (YT type, no bias).
// ---------------------------------------------------------------------------
template <int MODE, typename YT>
__device__ __forceinline__ void g256_body(const f16* __restrict__ X,
                                          const f16* __restrict__ W,
                                          const float* __restrict__ bias,
                                          YT* __restrict__ Y,
                                          int Ndim, int Kdim, int kbeg, int kend,
                                          int m0, int n0, f16* sA, f16* sB) {
    const int NT = (kend - kbeg) >> 6;
    const int t = threadIdx.x;
    const int lane = t & 63, w = t >> 6;
    const int wr = w >> 2, wc = w & 3;              // 2 x 4 wave grid
    const int lr = lane & 15, kq = lane >> 4;

    const int rh0 = t >> 3;                         // 0..63
    const int gc0 = (t & 7) ^ (rh0 & 7);            // pre-swizzled granule
    const f16* Asrc = X + (size_t)(m0 + rh0) * Kdim + kbeg + gc0 * 8;
    const f16* Bsrc = W + (size_t)(n0 + rh0) * Kdim + kbeg + gc0 * 8;

    f32x4 acc[8][4] = {};

#define STG_A(kt_) do { f16* d_ = sA + ((kt_) & 1) * 16384 + t * 8;            \
        const f16* s_ = Asrc + (size_t)(kt_) * 64;                             \
        __builtin_amdgcn_global_load_lds((const unsigned*)s_, (unsigned*)d_, 16, 0, 0); \
        __builtin_amdgcn_global_load_lds((const unsigned*)(s_ + (size_t)64 * Kdim),  (unsigned*)(d_ + 4096), 16, 0, 0);  \
        __builtin_amdgcn_global_load_lds((const unsigned*)(s_ + (size_t)128 * Kdim), (unsigned*)(d_ + 8192), 16, 0, 0);  \
        __builtin_amdgcn_global_load_lds((const unsigned*)(s_ + (size_t)192 * Kdim), (unsigned*)(d_ + 12288), 16, 0, 0); \
    } while (0)
#define STG_B(kt_) do { f16* d_ = sB + ((kt_) & 1) * 16384 + t * 8;            \
        const f16* s_ = Bsrc + (size_t)(kt_) * 64;                             \
        __builtin_amdgcn_global_load_lds((const unsigned*)s_, (unsigned*)d_, 16, 0, 0); \
        __builtin_amdgcn_global_load_lds((const unsigned*)(s_ + (size_t)64 * Kdim),  (unsigned*)(d_ + 4096), 16, 0, 0);  \
        __builtin_amdgcn_global_load_lds((const unsigned*)(s_ + (size_t)128 * Kdim), (unsigned*)(d_ + 8192), 16, 0, 0);  \
        __builtin_amdgcn_global_load_lds((const unsigned*)(s_ + (size_t)192 * Kdim), (unsigned*)(d_ + 12288), 16, 0, 0); \
    } while (0)

    STG_A(0); STG_B(0);
    if (NT > 1) {
        STG_A(1); STG_B(1);
        asm volatile("s_waitcnt vmcnt(8)");
    } else {
        asm volatile("s_waitcnt vmcnt(0)");
    }
    __builtin_amdgcn_s_barrier();

    for (int kt = 0; kt < NT; ++kt) {
        const int p = kt & 1;
        const f16* cA = sA + p * 16384;
        const f16* cB = sB + p * 16384;
        f16x8 a[4][2], b0[2][2], b1[2][2];

        // ---- ph1: quadrant (rows 4..7, cols 0..1)
#pragma unroll
        for (int i = 0; i < 4; ++i) {
            const int r = wr * 128 + (i + 4) * 16 + lr;
#pragma unroll
            for (int ks = 0; ks < 2; ++ks)
                a[i][ks] = *(const f16x8*)(cA + r * 64 + (((ks * 4 + kq) ^ (r & 7)) * 8));
        }
#pragma unroll
        for (int j = 0; j < 2; ++j) {
            const int rb = wc * 64 + j * 16 + lr;
#pragma unroll
            for (int ks = 0; ks < 2; ++ks)
                b0[j][ks] = *(const f16x8*)(cB + rb * 64 + (((ks * 4 + kq) ^ (rb & 7)) * 8));
        }
        __builtin_amdgcn_s_barrier();
        __builtin_amdgcn_s_setprio(1);
#pragma unroll
        for (int ks = 0; ks < 2; ++ks)
#pragma unroll
            for (int i = 0; i < 4; ++i)
#pragma unroll
                for (int j = 0; j < 2; ++j)
                    acc[i + 4][j] = __builtin_amdgcn_mfma_f32_16x16x32_f16(
                        a[i][ks], b0[j][ks], acc[i + 4][j], 0, 0, 0);
        __builtin_amdgcn_s_setprio(0);
        __builtin_amdgcn_s_barrier();

        // ---- ph2: quadrant (rows 4..7, cols 2..3)
#pragma unroll
        for (int j = 0; j < 2; ++j) {
            const int rb = wc * 64 + (j + 2) * 16 + lr;
#pragma unroll
            for (int ks = 0; ks < 2; ++ks)
                b1[j][ks] = *(const f16x8*)(cB + rb * 64 + (((ks * 4 + kq) ^ (rb & 7)) * 8));
        }
        __builtin_amdgcn_s_barrier();
        __builtin_amdgcn_s_setprio(1);
#pragma unroll
        for (int ks = 0; ks < 2; ++ks)
#pragma unroll
            for (int i = 0; i < 4; ++i)
#pragma unroll
                for (int j = 0; j < 2; ++j)
                    acc[i + 4][j + 2] = __builtin_amdgcn_mfma_f32_16x16x32_f16(
                        a[i][ks], b1[j][ks], acc[i + 4][j + 2], 0, 0, 0);
        __builtin_amdgcn_s_setprio(0);
        __builtin_amdgcn_s_barrier();

        // ---- ph3: quadrant (rows 0..3, cols 0..1); stage B(kt+2) -> cB
#pragma unroll
        for (int i = 0; i < 4; ++i) {
            const int r = wr * 128 + i * 16 + lr;
#pragma unroll
            for (int ks = 0; ks < 2; ++ks)
                a[i][ks] = *(const f16x8*)(cA + r * 64 + (((ks * 4 + kq) ^ (r & 7)) * 8));
        }
        if (kt + 2 < NT) STG_B(kt + 2);
        __builtin_amdgcn_s_barrier();
        __builtin_amdgcn_s_setprio(1);
#pragma unroll
        for (int ks = 0; ks < 2; ++ks)
#pragma unroll
            for (int i = 0; i < 4; ++i)
#pragma unroll
                for (int j = 0; j < 2; ++j)
                    acc[i][j] = __builtin_amdgcn_mfma_f32_16x16x32_f16(
                        a[i][ks], b0[j][ks], acc[i][j], 0, 0, 0);
        __builtin_amdgcn_s_setprio(0);
        __builtin_amdgcn_s_barrier();

        // ---- ph4: quadrant (rows 0..3, cols 2..3); stage A(kt+2) -> cA
        if (kt + 2 < NT) STG_A(kt + 2);
        __builtin_amdgcn_s_setprio(1);
#pragma unroll
        for (int ks = 0; ks < 2; ++ks)
#pragma unroll
            for (int i = 0; i < 4; ++i)
#pragma unroll
                for (int j = 0; j < 2; ++j)
                    acc[i][j + 2] = __builtin_amdgcn_mfma_f32_16x16x32_f16(
                        a[i][ks], b1[j][ks], acc[i][j + 2], 0, 0, 0);
        __builtin_amdgcn_s_setprio(0);
        if (kt + 2 < NT) asm volatile("s_waitcnt vmcnt(8)");
        else             asm volatile("s_waitcnt vmcnt(0)");
        __builtin_amdgcn_s_barrier();
    }
#undef STG_A
#undef STG_B

    // epilogue
#pragma unroll
    for (int j = 0; j < 4; ++j) {
        const int col = n0 + wc * 64 + j * 16 + lr;
        const float bcol = (MODE == 3) ? 0.f : bias[col];
#pragma unroll
        for (int i = 0; i < 8; ++i) {
#pragma unroll
            for (int rr = 0; rr < 4; ++rr) {
                const int row = m0 + wr * 128 + i * 16 + kq * 4 + rr;
                float v = acc[i][j][rr] + bcol;
                store_val(&Y[(size_t)row * Ndim + col], v);
            }
        }
    }
}

// FFN2 split-K=3 (27/27/26 K-tiles per z), f16 partials (halved traffic;
// quantization ~5e-4 abs, far below the 0.03125 passing absmax).
__global__ __launch_bounds__(512, 2) void gemm256_sk(const f16* __restrict__ X,
                                                     const f16* __restrict__ W,
                                                     f16* __restrict__ p0,
                                                     f16* __restrict__ p1,
                                                     f16* __restrict__ p2,
                                                     int Ndim, int Kdim) {
    __shared__ f16 sA[2 * 16384];
    __shared__ f16 sB[2 * 16384];
    const int z = blockIdx.z;
    f16* __restrict__ Y = (z == 0) ? p0 : (z == 1) ? p1 : p2;
    const int kbeg = z * 1728;
    const int kend = (z == 2) ? Kdim : kbeg + 1728;
    g256_body<3, f16>(X, W, nullptr, Y, Ndim, Kdim, kbeg, kend,
                      blockIdx.x * 256, blockIdx.y * 256, sA, sB);
}

// Fused QKV GEMM: W = [Wq;Wk;Wv] contiguous [3840,1280]; out [4096,3840] f16.
__global__ __launch_bounds__(512, 2) void gemm256_qkv(const f16* __restrict__ X,
                                                      const f16* __restrict__ Wqkv,
                                                      const float* __restrict__ bq,
                                                      const float* __restrict__ bk,
                                                      const float* __restrict__ bv,
                                                      f16* __restrict__ Y) {
    __shared__ f16 sA[2 * 16384];
    __shared__ f16 sB[2 * 16384];
    const int nt = blockIdx.y;                    // 0..14
    const int g = nt / 5;
    const float* bsel = (g == 0) ? bq : (g == 1) ? bk : bv;
    g256_body<0, f16>(X, Wqkv, bsel - (size_t)g * 1280, Y, QS_, H_, 0, H_,
                      blockIdx.x * 256, nt * 256, sA, sB);
}

// Split-K reduce: out = p0 + p1 + p2 (f16 partials) + bias[col] + res(f16).
// 8 elements/thread (f16x8 loads).
__global__ __launch_bounds__(256) void reduce3_kernel(const f16* __restrict__ p0,
                                                      const f16* __restrict__ p1,
                                                      const f16* __restrict__ p2,
                                                      const float* __restrict__ bias,
                                                      const f16* __restrict__ res,
                                                      float* __restrict__ out) {
    int i = blockIdx.x * 256 + threadIdx.x;       // x8 element-group index
    int col = (i * 8) % H_;                       // H_ % 8 == 0: no row crossing
    f16x8 a = ((const f16x8*)p0)[i];
    f16x8 b = ((const f16x8*)p1)[i];
    f16x8 c = ((const f16x8*)p2)[i];
    f32x4 bc0 = *(const f32x4*)(bias + col);
    f32x4 bc1 = *(const f32x4*)(bias + col + 4);
    f16x8 r = ((const f16x8*)res)[i];
    f32x4 o0, o1;
#pragma unroll
    for (int e = 0; e < 4; e++) {
        o0[e] = (float)a[e] + (float)b[e] + (float)c[e] + bc0[e] + (float)r[e];
        o1[e] = (float)a[e + 4] + (float)b[e + 4] + (float)c[e + 4] + bc1[e] + (float)r[e + 4];
    }
    ((f32x4*)out)[i * 2] = o0;
    ((f32x4*)out)[i * 2 + 1] = o1;
}

// ---------------------------------------------------------------------------
// Flash attention w/ MFMA, no-max exp2 softmax (log2-domain scores).
// Reads the fused QKV buffer (row stride QS_=3840; q/k/v at +0/+1280/+2560).
// Bias staged via sP aliasing; K/V/bias prefetched 1 tile ahead; sP
// wave-private => no mid barrier. Output xpre in f16 (h + ctx).
// ---------------------------------------------------------------------------
__global__ __launch_bounds__(256) void attn_kernel(const f16* __restrict__ qkv,
                                                   const f16* __restrict__ bb,
                                                   const float* __restrict__ hin,
                                                   f16* __restrict__ xpre) {
    __shared__ f16 sK[64 * 72];
    __shared__ f16 sVT[64 * 72];   // [d][m ^ 8*(d>>3&7)] swizzled
    __shared__ f16 sP[64 * 72];    // bias tile staged here, then P in-place

    const int t = threadIdx.x;
    const int w = t >> 6, lane = t & 63;
    const int lr = lane & 15, kq = lane >> 4;
    // bijective XCD-chunked swizzle: nwg = 16*20*4 = 1280, 1280/8 = 160.
    const int gid = blockIdx.x + 16 * (blockIdx.y + 20 * blockIdx.z);
    const int wk = (gid & 7) * 160 + (gid >> 3);
    const int l0 = (wk & 15) * 64;
    const int hb = wk >> 4;
    const int h = hb % 20, b = hb / 20;
    const size_t base  = (size_t)b * S_ * H_ + (size_t)h * DH_;     // hin/xpre
    const size_t baseq = (size_t)b * S_ * QS_ + (size_t)h * DH_;    // fused qkv
    const size_t kbase = baseq + 1280;
    const size_t vbase = baseq + 2560;

    const int kr0 = t >> 3, kc8 = (t & 7) * 8;
    const int vr2 = (t >> 3) * 2, vc8 = (t & 7) * 8;
    const int vmsw = vr2 ^ vc8;
    const int br = t >> 2, bc16 = (t & 3) * 16;
    const f16* bbrow0 = bb + ((size_t)b * S_ + l0 + br) * S_;

    // T14 prologue: issue tile-0 K/V/bias loads; land under Q reg loads.
    f16x8 kA0 = *(const f16x8*)&qkv[kbase + (size_t)kr0 * QS_ + kc8];
    f16x8 kA1 = *(const f16x8*)&qkv[kbase + (size_t)(kr0 + 32) * QS_ + kc8];
    f16x8 vA0 = *(const f16x8*)&qkv[vbase + (size_t)vr2 * QS_ + vc8];
    f16x8 vA1 = *(const f16x8*)&qkv[vbase + (size_t)(vr2 + 1) * QS_ + vc8];
    f16x8 bA0 = *(const f16x8*)(bbrow0 + bc16);
    f16x8 bA1 = *(const f16x8*)(bbrow0 + bc16 + 8);

    // Q fragments direct to regs (scaled).
    f16x8 afq[2];
#pragma unroll
    for (int ks = 0; ks < 2; ks++) {
        f16x8 qv = *(const f16x8*)&qkv[baseq + (size_t)(l0 + w * 16 + lr) * QS_ + ks * 32 + kq * 8];
#pragma unroll
        for (int e = 0; e < 8; e++) qv[e] = (f16)((float)qv[e] * (0.125f * LOG2E));
        afq[ks] = qv;
    }

    f32x4 acc_o[4] = {};
    float lstate[4] = {};

    for (int mt = 0; mt < 16; mt++) {
        __syncthreads();   // prev tile's QK/PV done with sK/sVT/sP
        *(f16x8*)&sK[kr0 * 72 + kc8] = kA0;
        *(f16x8*)&sK[(kr0 + 32) * 72 + kc8] = kA1;
#pragma unroll
        for (int e = 0; e < 8; e++) {
            f16x2 pk = {vA0[e], vA1[e]};
            *(f16x2*)&sVT[(vc8 + e) * 72 + vmsw] = pk;
        }
        *(f16x8*)&sP[br * 72 + bc16] = bA0;
        *(f16x8*)&sP[br * 72 + bc16 + 8] = bA1;
        const int m1 = ((mt + 1) & 15) * 64;   // wraps on last iter (harmless)
        f16x8 kB0 = *(const f16x8*)&qkv[kbase + (size_t)(m1 + kr0) * QS_ + kc8];
        f16x8 kB1 = *(const f16x8*)&qkv[kbase + (size_t)(m1 + kr0 + 32) * QS_ + kc8];
        f16x8 vB0 = *(const f16x8*)&qkv[vbase + (size_t)(m1 + vr2) * QS_ + vc8];
        f16x8 vB1 = *(const f16x8*)&qkv[vbase + (size_t)(m1 + vr2 + 1) * QS_ + vc8];
        f16x8 bB0 = *(const f16x8*)(bbrow0 + m1 + bc16);
        f16x8 bB1 = *(const f16x8*)(bbrow0 + m1 + bc16 + 8);
        __syncthreads();

        f32x4 sacc[4] = {};
        __builtin_amdgcn_s_setprio(1);
#pragma unroll
        for (int ks = 0; ks < 2; ks++)
#pragma unroll
            for (int j = 0; j < 4; j++) {
                f16x8 bk = *(const f16x8*)&sK[(j * 16 + lr) * 72 + ks * 32 + kq * 8];
                sacc[j] = __builtin_amdgcn_mfma_f32_16x16x32_f16(afq[ks], bk, sacc[j], 0, 0, 0);
            }
        __builtin_amdgcn_s_setprio(0);

        // bias from sP; P written back to the same wave-private addresses.
#pragma unroll
        for (int j = 0; j < 4; j++)
#pragma unroll
            for (int rr = 0; rr < 4; rr++) {
                const int sp_addr = (w * 16 + kq * 4 + rr) * 72 + j * 16 + lr;
                float p = __builtin_exp2f(sacc[j][rr] + (float)sP[sp_addr]);
                lstate[rr] += p;
                sP[sp_addr] = (f16)p;
            }
        // no barrier: sP rows w*16..w*16+15 are wave-private; DS is in-order.

        f16x8 ap[2];
        ap[0] = *(const f16x8*)&sP[(w * 16 + lr) * 72 + kq * 8];
        ap[1] = *(const f16x8*)&sP[(w * 16 + lr) * 72 + 32 + kq * 8];
        __builtin_amdgcn_s_setprio(1);
#pragma unroll
        for (int ks = 0; ks < 2; ks++)
#pragma unroll
            for (int j2 = 0; j2 < 4; j2++) {
                int d = j2 * 16 + lr;
                int s_ = (d >> 3) & 7;
                f16x8 bv = *(const f16x8*)&sVT[d * 72 + 8 * (((ks << 2) + kq) ^ s_)];
                acc_o[j2] = __builtin_amdgcn_mfma_f32_16x16x32_f16(ap[ks], bv, acc_o[j2], 0, 0, 0);
            }
        __builtin_amdgcn_s_setprio(0);
        kA0 = kB0; kA1 = kB1; vA0 = vB0; vA1 = vB1; bA0 = bB0; bA1 = bB1;
    }

#pragma unroll
    for (int rr = 0; rr < 4; rr++) {
#pragma unroll
        for (int off = 8; off >= 1; off >>= 1) lstate[rr] += __shfl_xor(lstate[rr], off);
    }

#pragma unroll
    for (int rr = 0; rr < 4; rr++) {
        float linv = 1.0f / lstate[rr];
        int tok = l0 + w * 16 + kq * 4 + rr;
        size_t obase = base + (size_t)tok * H_;
#pragma unroll
        for (int j2 = 0; j2 < 4; j2++) {
            int d = j2 * 16 + lr;
            xpre[obase + d] = (f16)(hin[obase + d] + acc_o[j2][rr] * linv);
        }
    }
}

// ---------------------------------------------------------------------------
// LayerNorm over H=1280; one block per row. f16 in, f16 out (f32 math).
// ---------------------------------------------------------------------------
__global__ __launch_bounds__(256) void ln_kernel(const f16* __restrict__ xpre,
                                                 const float* __restrict__ g,
                                                 const float* __restrict__ bb,
                                                 f16* __restrict__ xln) {
    int row = blockIdx.x, t = threadIdx.x;
    const f16* xr = xpre + (size_t)row * H_;
    float xv[5], s1 = 0.f, s2 = 0.f;
#pragma unroll
    for (int i = 0; i < 5; i++) {
        float v = (float)xr[t + 256 * i];
        xv[i] = v; s1 += v; s2 += v * v;
    }
#pragma unroll
    for (int o = 32; o >= 1; o >>= 1) { s1 += __shfl_xor(s1, o); s2 += __shfl_xor(s2, o); }
    __shared__ float r1[4], r2[4];
    int wv = t >> 6, lane = t & 63;
    if (lane == 0) { r1[wv] = s1; r2[wv] = s2; }
    __syncthreads();
    float m1 = (r1[0] + r1[1] + r1[2] + r1[3]) * (1.0f / H_);
    float m2 = (r2[0] + r2[1] + r2[2] + r2[3]) * (1.0f / H_);
    float rstd = rsqrtf(m2 - m1 * m1 + 1e-5f);
#pragma unroll
    for (int i = 0; i < 5; i++) {
        int c = t + 256 * i;
        float v = (xv[i] - m1) * rstd * g[c] + bb[c];
        xln[(size_t)row * H_ + c] = (f16)v;
    }
}

// ---------------------------------------------------------------------------
extern "C" void kernel_launch(void* const* d_in, const int* in_sizes, int n_in,
                              void* d_out, int out_size, void* d_ws, size_t ws_size,
                              hipStream_t stream) {
    (void)in_sizes; (void)n_in; (void)out_size; (void)ws_size;
    const float* hin  = (const float*)d_in[0];
    const float* mask = (const float*)d_in[1];
    const float* Wq = (const float*)d_in[2];  const float* bq = (const float*)d_in[3];
    const float* Wk = (const float*)d_in[4];  const float* bk = (const float*)d_in[5];
    const float* Wv = (const float*)d_in[6];  const float* bv = (const float*)d_in[7];
    const float* Wct1 = (const float*)d_in[8];  const float* bct1 = (const float*)d_in[9];
    const float* Wct2 = (const float*)d_in[10]; const float* bct2 = (const float*)d_in[11];
    const float* Mg = (const float*)d_in[12];   const float* bscale = (const float*)d_in[13];
    const float* Wptm = (const float*)d_in[14]; const float* bptm = (const float*)d_in[15];
    const float* lng = (const float*)d_in[16];  const float* lnb = (const float*)d_in[17];
    const float* Wf1 = (const float*)d_in[18];  const float* bf1 = (const float*)d_in[19];
    const float* Wf2 = (const float*)d_in[20];  const float* bf2 = (const float*)d_in[21];

    char* ws = (char*)d_ws;
    const size_t SZ_PT  = (size_t)B_ * S_ * P_ * 4;       // 131072
    const size_t SZ_H16 = (size_t)B_ * S_ * H_ * 2;       // 10485760 (f16)
    const size_t SZ_H32 = (size_t)B_ * S_ * H_ * 4;       // 20971520 (f32)
    const size_t SZ_WH  = (size_t)H_ * H_ * 2;            // 3276800
    const size_t SZ_WI  = (size_t)I_ * H_ * 2;            // 13107200
    float* ptm  = (float*)(ws + 256);
    float* tg   = (float*)(ws + 256 + SZ_PT);
    char* A0    = ws + 256 + 2 * SZ_PT;
    f16* hin16  = (f16*)(A0);
    f16* qkvb   = (f16*)(A0 + SZ_H16);         // fused [4096,3840] = 31.5 MB
    f16* xpre   = (f16*)(A0 + 4 * SZ_H16);     // f16 (10.5 MB)
    f16* xln    = (f16*)(A0 + 4 * SZ_H16 + SZ_H32);
    f16* bbias  = (f16*)(A0 + 5 * SZ_H16 + SZ_H32);       // 8.39 MB
    char* WA    = A0 + 5 * SZ_H16 + SZ_H32 + (size_t)B_ * S_ * S_ * 2;
    f16* Wq16   = (f16*)(WA);                  // [Wq;Wk;Wv] fused [3840,1280]
    f16* Wk16   = (f16*)(WA + SZ_WH);
    f16* Wv16   = (f16*)(WA + 2 * SZ_WH);
    f16* Wf116  = (f16*)(WA + 3 * SZ_WH);
    f16* Wf216  = (f16*)(WA + 3 * SZ_WH + SZ_WI);
    f16* g1     = (f16*)(A0);                  // aliases hin16+qkvb (dead by FFN1)
    f16* pbuf   = (f16*)(WA + 3 * SZ_WH + 2 * SZ_WI);     // 3 x 10.5 MB f16 partials

    // prep: 1024 ptm blocks + 17600 cvt blocks (3x1600 + 2x6400) fused.
    prep_kernel<<<1024 + 17600, 256, 0, stream>>>(
        hin, Wptm, bptm, Mg, Wct1, bct1, Wct2, bct2, ptm, tg, hin16,
        Wq, Wk, Wv, Wf1, Wf2, Wq16, Wk16, Wv16, Wf116, Wf216);
    bias_kernel<<<B_ * S_, 256, 0, stream>>>(tg, ptm, mask, bscale, bbias);
    // Fused QKV: deep-pipelined 256^2, 16 x 15 = 240 blocks (one CU round).
    gemm256_qkv<<<dim3(16, 15), 512, 0, stream>>>(hin16, Wq16, bq, bk, bv, qkvb);
    attn_kernel<<<dim3(S_ / 64, NH_, B_), 256, 0, stream>>>(qkvb, bbias, hin, xpre);
    ln_kernel<<<B_ * S_, 256, 0, stream>>>(xpre, lng, lnb, xln);
    // FFN1: m97 128^2 (2 blocks/CU; measured 77-78 us vs 81.4 for 256x320).
    gemm128<1, f16><<<dim3(32, I_ / 128), 256, 0, stream>>>(xln, Wf116, bf1, g1, I_, H_);
    // FFN2 deep-pipelined 256^2 split-K=3, f16 partials: 240 blocks (1 round)
    gemm256_sk<<<dim3(16, H_ / 256, 3), 512, 0, stream>>>(
        g1, Wf216, pbuf, pbuf + (size_t)B_ * S_ * H_, pbuf + 2 * (size_t)B_ * S_ * H_,
        H_, I_);
    reduce3_kernel<<<(B_ * S_ * H_) / 8 / 256, 256, 0, stream>>>(
        pbuf, pbuf + (size_t)B_ * S_ * H_, pbuf + 2 * (size_t)B_ * S_ * H_,
        bf2, xln, (float*)d_out);
}

// Round 10
// 419.454 us; speedup vs baseline: 1.0685x; 1.0685x over previous
//
#include <hip/hip_runtime.h>
#include <math.h>

typedef _Float16 f16;
typedef _Float16 f16x2 __attribute__((ext_vector_type(2)));
typedef _Float16 f16x8 __attribute__((ext_vector_type(8)));
typedef _Float16 f16x4 __attribute__((ext_vector_type(4)));
typedef float f32x4 __attribute__((ext_vector_type(4)));

#define B_ 4
#define S_ 1024
#define H_ 1280
#define NH_ 20
#define DH_ 64
#define I_ 5120
#define C_ 13
#define P_ 8
#define QS_ 3840                      // fused QKV row stride
#define LOG2E 1.44269504088896f

__device__ __forceinline__ void store_val(float* p, float v) { *p = v; }
__device__ __forceinline__ void store_val(f16* p, float v) { *p = (f16)v; }

// Exact-GELU via Abramowitz-Stegun 7.1.26 erf (|eps| <= 1.5e-7; << f16 ulp).
__device__ __forceinline__ float fast_gelu(float x) {
    float ax = 0.70710678118654752f * fabsf(x);
    float t = __builtin_amdgcn_rcpf(1.0f + 0.3275911f * ax);
    float p = t * (0.254829592f + t * (-0.284496736f + t * (1.421413741f
              + t * (-1.453152027f + t * 1.061405429f))));
    float e = __builtin_exp2f(-(LOG2E) * ax * ax);
    float er = 1.0f - p * e;                       // erf(|x|/sqrt2)
    float cdf = 0.5f + 0.5f * (x >= 0.0f ? er : -er);
    return x * cdf;
}

// tanh via exp2 + rcp (~5e-7 abs err). Input clamped to +-20.
__device__ __forceinline__ float fast_tanh(float x) {
    x = fminf(fmaxf(x, -20.0f), 20.0f);
    float e = __builtin_exp2f(x * (2.0f * LOG2E));
    return (e - 1.0f) * __builtin_amdgcn_rcpf(e + 1.0f);
}

// ---------------------------------------------------------------------------
// prep_kernel: blocks 0..1023 = ptm (softmax(h@Wptm^T+b) and t = ptm@R, one
// wave per token row; also emits hin16). Blocks 1024.. = f32->f16 weight
// conversion (Wq/Wk/Wv: 1600 blocks each; Wf1/Wf2: 6400 each).
// ---------------------------------------------------------------------------
__global__ __launch_bounds__(256) void prep_kernel(const float* __restrict__ hin,
                                                   const float* __restrict__ Wptm,
                                                   const float* __restrict__ bptm,
                                                   const float* __restrict__ Mg,
                                                   const float* __restrict__ W1,
                                                   const float* __restrict__ b1,
                                                   const float* __restrict__ W2,
                                                   const float* __restrict__ b2,
                                                   float* __restrict__ ptm,
                                                   float* __restrict__ tg,
                                                   f16* __restrict__ hin16,
                                                   const float* __restrict__ Wq,
                                                   const float* __restrict__ Wk,
                                                   const float* __restrict__ Wv,
                                                   const float* __restrict__ Wf1,
                                                   const float* __restrict__ Wf2,
                                                   f16* __restrict__ Wq16,
                                                   f16* __restrict__ Wk16,
                                                   f16* __restrict__ Wv16,
                                                   f16* __restrict__ Wf116,
                                                   f16* __restrict__ Wf216) {
    const int bid = blockIdx.x;
    int t = threadIdx.x;
    if (bid >= 1024) {
        const int cb = bid - 1024;
        const float* src; f16* dst; int base;
        if (cb < 4800) {
            const int s = cb / 1600;
            src = (s == 0) ? Wq : (s == 1) ? Wk : Wv;
            dst = (s == 0) ? Wq16 : (s == 1) ? Wk16 : Wv16;
            base = (cb - s * 1600) * 256;
        } else if (cb < 11200) {
            src = Wf1; dst = Wf116; base = (cb - 4800) * 256;
        } else {
            src = Wf2; dst = Wf216; base = (cb - 11200) * 256;
        }
        const int i = base + t;
        f32x4 v = ((const f32x4*)src)[i];
        f16x4 o;
#pragma unroll
        for (int e = 0; e < 4; e++) o[e] = (f16)v[e];
        ((f16x4*)dst)[i] = o;
        return;
    }

    __shared__ float o1[P_][C_];
    __shared__ float o2[C_][P_];
    __shared__ float R[P_ * P_];
    if (t < P_ * C_) {
        int p = t / C_, c = t % C_;
        float s = b1[p];
        for (int k = 0; k < C_; k++) s += Mg[k * C_ + c] * W1[p * C_ + k];
        o1[p][c] = s;
        int c2 = t / P_, p2 = t % P_;
        float s2 = b2[p2];
        for (int k = 0; k < C_; k++) s2 += Mg[c2 * C_ + k] * W2[p2 * C_ + k];
        o2[c2][p2] = s2;
    }
    __syncthreads();
    if (t < P_ * P_) {
        int p = t >> 3, q = t & 7;
        float s = 0.f;
        for (int c = 0; c < C_; c++) s += o1[p][c] * o2[c][q];
        R[t] = s;
    }
    __syncthreads();

    int wv = t >> 6, lane = t & 63;
    int row = bid * 4 + wv;
    const float* hrow = hin + (size_t)row * H_;
    f16* hrow16 = hin16 + (size_t)row * H_;
    float acc[P_] = {};
    for (int i = 0; i < H_ / 64; i++) {
        int k = lane + 64 * i;
        float hv = hrow[k];
        hrow16[k] = (f16)hv;
#pragma unroll
        for (int p = 0; p < P_; p++) acc[p] += hv * Wptm[p * H_ + k];
    }
#pragma unroll
    for (int p = 0; p < P_; p++) {
#pragma unroll
        for (int o = 32; o >= 1; o >>= 1) acc[p] += __shfl_xor(acc[p], o);
        acc[p] += bptm[p];
    }
    float mx = acc[0];
#pragma unroll
    for (int p = 1; p < P_; p++) mx = fmaxf(mx, acc[p]);
    float sum = 0.f;
#pragma unroll
    for (int p = 0; p < P_; p++) { acc[p] = expf(acc[p] - mx); sum += acc[p]; }
    float rinv = 1.f / sum;
#pragma unroll
    for (int p = 0; p < P_; p++) acc[p] *= rinv;
    float tv[P_];
#pragma unroll
    for (int d = 0; d < P_; d++) {
        float s = 0.f;
#pragma unroll
        for (int c = 0; c < P_; c++) s += acc[c] * R[c * P_ + d];
        tv[d] = s;
    }
    if (lane == 0) {
#pragma unroll
        for (int p = 0; p < P_; p++) {
            ptm[(size_t)row * P_ + p] = acc[p];
            tg[(size_t)row * P_ + p]  = tv[p];
        }
    }
}

// ---------------------------------------------------------------------------
// Bias precompute, LOG2E-folded: bb = (tanh(dot8)*bscale + maskterm) * LOG2E
// ---------------------------------------------------------------------------
__global__ __launch_bounds__(256) void bias_kernel(const float* __restrict__ tg,
                                                   const float* __restrict__ ptm,
                                                   const float* __restrict__ mask,
                                                   const float* __restrict__ bscale_p,
                                                   f16* __restrict__ bb) {
    const int bl = blockIdx.x;          // b*1024 + l
    const int b = bl >> 10;
    const int t = threadIdx.x;
    __shared__ float tl[P_];
    if (t < P_) tl[t] = tg[(size_t)bl * P_ + t];
    __syncthreads();
    const float bscale = bscale_p[0];
    float t0 = tl[0], t1 = tl[1], t2 = tl[2], t3 = tl[3];
    float t4 = tl[4], t5 = tl[5], t6 = tl[6], t7 = tl[7];
#pragma unroll
    for (int i = 0; i < 4; i++) {
        int m = t + 256 * i;
        const float* pm = ptm + ((size_t)b * S_ + m) * P_;
        float4 p0 = *(const float4*)pm;
        float4 p1 = *(const float4*)(pm + 4);
        float d = t0 * p0.x + t1 * p0.y + t2 * p0.z + t3 * p0.w
                + t4 * p1.x + t5 * p1.y + t6 * p1.z + t7 * p1.w;
        float v = (fast_tanh(d) * bscale + (1.0f - mask[(size_t)b * S_ + m]) * (-30000.0f)) * LOG2E;
        bb[(size_t)bl * S_ + m] = (f16)v;
    }
}

// ---------------------------------------------------------------------------
// m97-style GEMM body: 128x128 tile, BK=64, global_load_lds width=16,
// XOR swizzle on the global-address side. 2 blocks/CU. (FFN1.)
// MODE 0: plain f16 out. MODE 1: fast exact GELU.
// ---------------------------------------------------------------------------
template <int MODE, typename YT>
__device__ __forceinline__ void gemm_body(const f16* __restrict__ X,
                                          const f16* __restrict__ W,
                                          const float* __restrict__ bias,
                                          YT* __restrict__ Y,
                                          int Ndim, int Kdim, int kbeg, int kend,
                                          int m0, int n0, f16* sA, f16* sB) {
    const int t = threadIdx.x;
    const int lane = t & 63, w = t >> 6;
    const int wr = w >> 1, wc = w & 1;
    const int lr = lane & 15, kq = lane >> 4;

    f32x4 acc[4][4] = {};

    int s_row[4], s_gc[4];
#pragma unroll
    for (int inst = 0; inst < 4; inst++) {
        int ci = t + 256 * inst;
        s_row[inst] = ci >> 3;
        s_gc[inst] = (ci & 7) ^ (s_row[inst] & 7);
    }

    for (int k0 = kbeg; k0 < kend; k0 += 64) {
        __syncthreads();
#pragma unroll
        for (int inst = 0; inst < 4; inst++) {
            int ci = t + 256 * inst;
            __builtin_amdgcn_global_load_lds(
                (const unsigned*)(X + (size_t)(m0 + s_row[inst]) * Kdim + k0 + s_gc[inst] * 8),
                (unsigned*)(sA + ci * 8), 16, 0, 0);
        }
#pragma unroll
        for (int inst = 0; inst < 4; inst++) {
            int ci = t + 256 * inst;
            __builtin_amdgcn_global_load_lds(
                (const unsigned*)(W + (size_t)(n0 + s_row[inst]) * Kdim + k0 + s_gc[inst] * 8),
                (unsigned*)(sB + ci * 8), 16, 0, 0);
        }
        __syncthreads();
#pragma unroll
        for (int ks = 0; ks < 2; ks++) {
            f16x8 af[4], bf[4];
#pragma unroll
            for (int i = 0; i < 4; i++) {
                int row = wr * 64 + i * 16 + lr;
                int cl = (ks * 4 + kq) ^ (row & 7);
                af[i] = *(const f16x8*)(sA + row * 64 + cl * 8);
            }
#pragma unroll
            for (int j = 0; j < 4; j++) {
                int row = wc * 64 + j * 16 + lr;
                int cl = (ks * 4 + kq) ^ (row & 7);
                bf[j] = *(const f16x8*)(sB + row * 64 + cl * 8);
            }
#pragma unroll
            for (int i = 0; i < 4; i++)
#pragma unroll
                for (int j = 0; j < 4; j++)
                    acc[i][j] = __builtin_amdgcn_mfma_f32_16x16x32_f16(af[i], bf[j], acc[i][j], 0, 0, 0);
        }
    }
#pragma unroll
    for (int j = 0; j < 4; j++) {
        int col = n0 + wc * 64 + j * 16 + lr;
        float bcol = bias[col];
#pragma unroll
        for (int i = 0; i < 4; i++) {
#pragma unroll
            for (int rr = 0; rr < 4; rr++) {
                int row = m0 + wr * 64 + i * 16 + kq * 4 + rr;
                float v = acc[i][j][rr] + bcol;
                if (MODE == 1) v = fast_gelu(v);
                store_val(&Y[(size_t)row * Ndim + col], v);
            }
        }
    }
}

template <int MODE, typename YT>
__global__ __launch_bounds__(256, 2) void gemm128(const f16* __restrict__ X,
                                                  const f16* __restrict__ W,
                                                  const float* __restrict__ bias,
                                                  YT* __restrict__ Y,
                                                  int Ndim, int Kdim) {
    __shared__ f16 sA[128 * 64];
    __shared__ f16 sB[128 * 64];
    gemm_body<MODE, YT>(X, W, bias, Y, Ndim, Kdim, 0, Kdim,
                        blockIdx.x * 128, blockIdx.y * 128, sA, sB);
}

// ---------------------------------------------------------------------------
// Deep-pipelined 256x256 GEMM body: 8 waves (2x4), BK=64, double-buffered
// LDS, counted vmcnt(8) per K-tile. (QKV + FFN2-sk.)
// MODE 0: bias + f16 out. MODE 3: raw f32 partial (no bias).
// ---------------------------------------------------------------------------
template <int MODE, typename YT>
__device__ __forceinline__ void g256_body(const f16* __restrict__ X,
                                          const f16* __restrict__ W,
                                          const float* __restrict__ bias,
                                          YT* __restrict__ Y,
                                          int Ndim, int Kdim, int kbeg, int kend,
                                          int m0, int n0, f16* sA, f16* sB) {
    const int NT = (kend - kbeg) >> 6;
    const int t = threadIdx.x;
    const int lane = t & 63, w = t >> 6;
    const int wr = w >> 2, wc = w & 3;              // 2 x 4 wave grid
    const int lr = lane & 15, kq = lane >> 4;

    const int rh0 = t >> 3;                         // 0..63
    const int gc0 = (t & 7) ^ (rh0 & 7);            // pre-swizzled granule
    const f16* Asrc = X + (size_t)(m0 + rh0) * Kdim + kbeg + gc0 * 8;
    const f16* Bsrc = W + (size_t)(n0 + rh0) * Kdim + kbeg + gc0 * 8;

    f32x4 acc[8][4] = {};

#define STG_A(kt_) do { f16* d_ = sA + ((kt_) & 1) * 16384 + t * 8;            \
        const f16* s_ = Asrc + (size_t)(kt_) * 64;                             \
        __builtin_amdgcn_global_load_lds((const unsigned*)s_, (unsigned*)d_, 16, 0, 0); \
        __builtin_amdgcn_global_load_lds((const unsigned*)(s_ + (size_t)64 * Kdim),  (unsigned*)(d_ + 4096), 16, 0, 0);  \
        __builtin_amdgcn_global_load_lds((const unsigned*)(s_ + (size_t)128 * Kdim), (unsigned*)(d_ + 8192), 16, 0, 0);  \
        __builtin_amdgcn_global_load_lds((const unsigned*)(s_ + (size_t)192 * Kdim), (unsigned*)(d_ + 12288), 16, 0, 0); \
    } while (0)
#define STG_B(kt_) do { f16* d_ = sB + ((kt_) & 1) * 16384 + t * 8;            \
        const f16* s_ = Bsrc + (size_t)(kt_) * 64;                             \
        __builtin_amdgcn_global_load_lds((const unsigned*)s_, (unsigned*)d_, 16, 0, 0); \
        __builtin_amdgcn_global_load_lds((const unsigned*)(s_ + (size_t)64 * Kdim),  (unsigned*)(d_ + 4096), 16, 0, 0);  \
        __builtin_amdgcn_global_load_lds((const unsigned*)(s_ + (size_t)128 * Kdim), (unsigned*)(d_ + 8192), 16, 0, 0);  \
        __builtin_amdgcn_global_load_lds((const unsigned*)(s_ + (size_t)192 * Kdim), (unsigned*)(d_ + 12288), 16, 0, 0); \
    } while (0)

    STG_A(0); STG_B(0);
    if (NT > 1) {
        STG_A(1); STG_B(1);
        asm volatile("s_waitcnt vmcnt(8)");
    } else {
        asm volatile("s_waitcnt vmcnt(0)");
    }
    __builtin_amdgcn_s_barrier();

    for (int kt = 0; kt < NT; ++kt) {
        const int p = kt & 1;
        const f16* cA = sA + p * 16384;
        const f16* cB = sB + p * 16384;
        f16x8 a[4][2], b0[2][2], b1[2][2];

        // ---- ph1: quadrant (rows 4..7, cols 0..1)
#pragma unroll
        for (int i = 0; i < 4; ++i) {
            const int r = wr * 128 + (i + 4) * 16 + lr;
#pragma unroll
            for (int ks = 0; ks < 2; ++ks)
                a[i][ks] = *(const f16x8*)(cA + r * 64 + (((ks * 4 + kq) ^ (r & 7)) * 8));
        }
#pragma unroll
        for (int j = 0; j < 2; ++j) {
            const int rb = wc * 64 + j * 16 + lr;
#pragma unroll
            for (int ks = 0; ks < 2; ++ks)
                b0[j][ks] = *(const f16x8*)(cB + rb * 64 + (((ks * 4 + kq) ^ (rb & 7)) * 8));
        }
        __builtin_amdgcn_s_barrier();
        __builtin_amdgcn_s_setprio(1);
#pragma unroll
        for (int ks = 0; ks < 2; ++ks)
#pragma unroll
            for (int i = 0; i < 4; ++i)
#pragma unroll
                for (int j = 0; j < 2; ++j)
                    acc[i + 4][j] = __builtin_amdgcn_mfma_f32_16x16x32_f16(
                        a[i][ks], b0[j][ks], acc[i + 4][j], 0, 0, 0);
        __builtin_amdgcn_s_setprio(0);
        __builtin_amdgcn_s_barrier();

        // ---- ph2: quadrant (rows 4..7, cols 2..3)
#pragma unroll
        for (int j = 0; j < 2; ++j) {
            const int rb = wc * 64 + (j + 2) * 16 + lr;
#pragma unroll
            for (int ks = 0; ks < 2; ++ks)
                b1[j][ks] = *(const f16x8*)(cB + rb * 64 + (((ks * 4 + kq) ^ (rb & 7)) * 8));
        }
        __builtin_amdgcn_s_barrier();
        __builtin_amdgcn_s_setprio(1);
#pragma unroll
        for (int ks = 0; ks < 2; ++ks)
#pragma unroll
            for (int i = 0; i < 4; ++i)
#pragma unroll
                for (int j = 0; j < 2; ++j)
                    acc[i + 4][j + 2] = __builtin_amdgcn_mfma_f32_16x16x32_f16(
                        a[i][ks], b1[j][ks], acc[i + 4][j + 2], 0, 0, 0);
        __builtin_amdgcn_s_setprio(0);
        __builtin_amdgcn_s_barrier();

        // ---- ph3: quadrant (rows 0..3, cols 0..1); stage B(kt+2) -> cB
#pragma unroll
        for (int i = 0; i < 4; ++i) {
            const int r = wr * 128 + i * 16 + lr;
#pragma unroll
            for (int ks = 0; ks < 2; ++ks)
                a[i][ks] = *(const f16x8*)(cA + r * 64 + (((ks * 4 + kq) ^ (r & 7)) * 8));
        }
        if (kt + 2 < NT) STG_B(kt + 2);
        __builtin_amdgcn_s_barrier();
        __builtin_amdgcn_s_setprio(1);
#pragma unroll
        for (int ks = 0; ks < 2; ++ks)
#pragma unroll
            for (int i = 0; i < 4; ++i)
#pragma unroll
                for (int j = 0; j < 2; ++j)
                    acc[i][j] = __builtin_amdgcn_mfma_f32_16x16x32_f16(
                        a[i][ks], b0[j][ks], acc[i][j], 0, 0, 0);
        __builtin_amdgcn_s_setprio(0);
        __builtin_amdgcn_s_barrier();

        // ---- ph4: quadrant (rows 0..3, cols 2..3); stage A(kt+2) -> cA
        if (kt + 2 < NT) STG_A(kt + 2);
        __builtin_amdgcn_s_setprio(1);
#pragma unroll
        for (int ks = 0; ks < 2; ++ks)
#pragma unroll
            for (int i = 0; i < 4; ++i)
#pragma unroll
                for (int j = 0; j < 2; ++j)
                    acc[i][j + 2] = __builtin_amdgcn_mfma_f32_16x16x32_f16(
                        a[i][ks], b1[j][ks], acc[i][j + 2], 0, 0, 0);
        __builtin_amdgcn_s_setprio(0);
        if (kt + 2 < NT) asm volatile("s_waitcnt vmcnt(8)");
        else             asm volatile("s_waitcnt vmcnt(0)");
        __builtin_amdgcn_s_barrier();
    }
#undef STG_A
#undef STG_B

    // epilogue
#pragma unroll
    for (int j = 0; j < 4; ++j) {
        const int col = n0 + wc * 64 + j * 16 + lr;
        const float bcol = (MODE == 3) ? 0.f : bias[col];
#pragma unroll
        for (int i = 0; i < 8; ++i) {
#pragma unroll
            for (int rr = 0; rr < 4; ++rr) {
                const int row = m0 + wr * 128 + i * 16 + kq * 4 + rr;
                float v = acc[i][j][rr] + bcol;
                store_val(&Y[(size_t)row * Ndim + col], v);
            }
        }
    }
}

// FFN2 split-K=3 (27/27/26 K-tiles per z), raw f32 partials.
__global__ __launch_bounds__(512, 2) void gemm256_sk(const f16* __restrict__ X,
                                                     const f16* __restrict__ W,
                                                     float* __restrict__ p0,
                                                     float* __restrict__ p1,
                                                     float* __restrict__ p2,
                                                     int Ndim, int Kdim) {
    __shared__ f16 sA[2 * 16384];
    __shared__ f16 sB[2 * 16384];
    const int z = blockIdx.z;
    float* __restrict__ Y = (z == 0) ? p0 : (z == 1) ? p1 : p2;
    const int kbeg = z * 1728;
    const int kend = (z == 2) ? Kdim : kbeg + 1728;
    g256_body<3, float>(X, W, nullptr, Y, Ndim, Kdim, kbeg, kend,
                        blockIdx.x * 256, blockIdx.y * 256, sA, sB);
}

// Fused QKV GEMM: W = [Wq;Wk;Wv] contiguous [3840,1280]; out [4096,3840] f16.
__global__ __launch_bounds__(512, 2) void gemm256_qkv(const f16* __restrict__ X,
                                                      const f16* __restrict__ Wqkv,
                                                      const float* __restrict__ bq,
                                                      const float* __restrict__ bk,
                                                      const float* __restrict__ bv,
                                                      f16* __restrict__ Y) {
    __shared__ f16 sA[2 * 16384];
    __shared__ f16 sB[2 * 16384];
    const int nt = blockIdx.y;                    // 0..14
    const int g = nt / 5;
    const float* bsel = (g == 0) ? bq : (g == 1) ? bk : bv;
    g256_body<0, f16>(X, Wqkv, bsel - (size_t)g * 1280, Y, QS_, H_, 0, H_,
                      blockIdx.x * 256, nt * 256, sA, sB);
}

// Split-K reduce: out = p0 + p1 + p2 + bias[col] + res(f16), float4-vectorized.
__global__ __launch_bounds__(256) void reduce3_kernel(const float* __restrict__ p0,
                                                      const float* __restrict__ p1,
                                                      const float* __restrict__ p2,
                                                      const float* __restrict__ bias,
                                                      const f16* __restrict__ res,
                                                      float* __restrict__ out) {
    int i = blockIdx.x * 256 + threadIdx.x;       // float4 index
    int col = (i * 4) % H_;                       // H_ % 4 == 0: no row crossing
    f32x4 a = ((const f32x4*)p0)[i];
    f32x4 b = ((const f32x4*)p1)[i];
    f32x4 c = ((const f32x4*)p2)[i];
    f32x4 bc = *(const f32x4*)(bias + col);
    f16x4 r = ((const f16x4*)res)[i];
    f32x4 o;
#pragma unroll
    for (int e = 0; e < 4; e++) o[e] = a[e] + b[e] + c[e] + bc[e] + (float)r[e];
    ((f32x4*)out)[i] = o;
}

// ---------------------------------------------------------------------------
// Flash attention w/ MFMA, no-max exp2 softmax (log2-domain scores).
// Reads the fused QKV buffer (row stride QS_=3840; q/k/v at +0/+1280/+2560).
// Bias staged via sP aliasing; K/V/bias prefetched 1 tile ahead; sP
// wave-private => no mid barrier. Output xpre in f32 (h + ctx).
// ---------------------------------------------------------------------------
__global__ __launch_bounds__(256) void attn_kernel(const f16* __restrict__ qkv,
                                                   const f16* __restrict__ bb,
                                                   const float* __restrict__ hin,
                                                   float* __restrict__ xpre) {
    __shared__ f16 sK[64 * 72];
    __shared__ f16 sVT[64 * 72];   // [d][m ^ 8*(d>>3&7)] swizzled
    __shared__ f16 sP[64 * 72];    // bias tile staged here, then P in-place

    const int t = threadIdx.x;
    const int w = t >> 6, lane = t & 63;
    const int lr = lane & 15, kq = lane >> 4;
    // bijective XCD-chunked swizzle: nwg = 16*20*4 = 1280, 1280/8 = 160.
    const int gid = blockIdx.x + 16 * (blockIdx.y + 20 * blockIdx.z);
    const int wk = (gid & 7) * 160 + (gid >> 3);
    const int l0 = (wk & 15) * 64;
    const int hb = wk >> 4;
    const int h = hb % 20, b = hb / 20;
    const size_t base  = (size_t)b * S_ * H_ + (size_t)h * DH_;     // hin/xpre
    const size_t baseq = (size_t)b * S_ * QS_ + (size_t)h * DH_;    // fused qkv
    const size_t kbase = baseq + 1280;
    const size_t vbase = baseq + 2560;

    const int kr0 = t >> 3, kc8 = (t & 7) * 8;
    const int vr2 = (t >> 3) * 2, vc8 = (t & 7) * 8;
    const int vmsw = vr2 ^ vc8;
    const int br = t >> 2, bc16 = (t & 3) * 16;
    const f16* bbrow0 = bb + ((size_t)b * S_ + l0 + br) * S_;

    // T14 prologue: issue tile-0 K/V/bias loads; land under Q reg loads.
    f16x8 kA0 = *(const f16x8*)&qkv[kbase + (size_t)kr0 * QS_ + kc8];
    f16x8 kA1 = *(const f16x8*)&qkv[kbase + (size_t)(kr0 + 32) * QS_ + kc8];
    f16x8 vA0 = *(const f16x8*)&qkv[vbase + (size_t)vr2 * QS_ + vc8];
    f16x8 vA1 = *(const f16x8*)&qkv[vbase + (size_t)(vr2 + 1) * QS_ + vc8];
    f16x8 bA0 = *(const f16x8*)(bbrow0 + bc16);
    f16x8 bA1 = *(const f16x8*)(bbrow0 + bc16 + 8);

    // Q fragments direct to regs (scaled).
    f16x8 afq[2];
#pragma unroll
    for (int ks = 0; ks < 2; ks++) {
        f16x8 qv = *(const f16x8*)&qkv[baseq + (size_t)(l0 + w * 16 + lr) * QS_ + ks * 32 + kq * 8];
#pragma unroll
        for (int e = 0; e < 8; e++) qv[e] = (f16)((float)qv[e] * (0.125f * LOG2E));
        afq[ks] = qv;
    }

    f32x4 acc_o[4] = {};
    float lstate[4] = {};

    for (int mt = 0; mt < 16; mt++) {
        __syncthreads();   // prev tile's QK/PV done with sK/sVT/sP
        *(f16x8*)&sK[kr0 * 72 + kc8] = kA0;
        *(f16x8*)&sK[(kr0 + 32) * 72 + kc8] = kA1;
#pragma unroll
        for (int e = 0; e < 8; e++) {
            f16x2 pk = {vA0[e], vA1[e]};
            *(f16x2*)&sVT[(vc8 + e) * 72 + vmsw] = pk;
        }
        *(f16x8*)&sP[br * 72 + bc16] = bA0;
        *(f16x8*)&sP[br * 72 + bc16 + 8] = bA1;
        const int m1 = ((mt + 1) & 15) * 64;   // wraps on last iter (harmless)
        f16x8 kB0 = *(const f16x8*)&qkv[kbase + (size_t)(m1 + kr0) * QS_ + kc8];
        f16x8 kB1 = *(const f16x8*)&qkv[kbase + (size_t)(m1 + kr0 + 32) * QS_ + kc8];
        f16x8 vB0 = *(const f16x8*)&qkv[vbase + (size_t)(m1 + vr2) * QS_ + vc8];
        f16x8 vB1 = *(const f16x8*)&qkv[vbase + (size_t)(m1 + vr2 + 1) * QS_ + vc8];
        f16x8 bB0 = *(const f16x8*)(bbrow0 + m1 + bc16);
        f16x8 bB1 = *(const f16x8*)(bbrow0 + m1 + bc16 + 8);
        __syncthreads();

        f32x4 sacc[4] = {};
        __builtin_amdgcn_s_setprio(1);
#pragma unroll
        for (int ks = 0; ks < 2; ks++)
#pragma unroll
            for (int j = 0; j < 4; j++) {
                f16x8 bk = *(const f16x8*)&sK[(j * 16 + lr) * 72 + ks * 32 + kq * 8];
                sacc[j] = __builtin_amdgcn_mfma_f32_16x16x32_f16(afq[ks], bk, sacc[j], 0, 0, 0);
            }
        __builtin_amdgcn_s_setprio(0);

        // bias from sP; P written back to the same wave-private addresses.
#pragma unroll
        for (int j = 0; j < 4; j++)
#pragma unroll
            for (int rr = 0; rr < 4; rr++) {
                const int sp_addr = (w * 16 + kq * 4 + rr) * 72 + j * 16 + lr;
                float p = __builtin_exp2f(sacc[j][rr] + (float)sP[sp_addr]);
                lstate[rr] += p;
                sP[sp_addr] = (f16)p;
            }
        // no barrier: sP rows w*16..w*16+15 are wave-private; DS is in-order.

        f16x8 ap[2];
        ap[0] = *(const f16x8*)&sP[(w * 16 + lr) * 72 + kq * 8];
        ap[1] = *(const f16x8*)&sP[(w * 16 + lr) * 72 + 32 + kq * 8];
        __builtin_amdgcn_s_setprio(1);
#pragma unroll
        for (int ks = 0; ks < 2; ks++)
#pragma unroll
            for (int j2 = 0; j2 < 4; j2++) {
                int d = j2 * 16 + lr;
                int s_ = (d >> 3) & 7;
                f16x8 bv = *(const f16x8*)&sVT[d * 72 + 8 * (((ks << 2) + kq) ^ s_)];
                acc_o[j2] = __builtin_amdgcn_mfma_f32_16x16x32_f16(ap[ks], bv, acc_o[j2], 0, 0, 0);
            }
        __builtin_amdgcn_s_setprio(0);
        kA0 = kB0; kA1 = kB1; vA0 = vB0; vA1 = vB1; bA0 = bB0; bA1 = bB1;
    }

#pragma unroll
    for (int rr = 0; rr < 4; rr++) {
#pragma unroll
        for (int off = 8; off >= 1; off >>= 1) lstate[rr] += __shfl_xor(lstate[rr], off);
    }

#pragma unroll
    for (int rr = 0; rr < 4; rr++) {
        float linv = 1.0f / lstate[rr];
        int tok = l0 + w * 16 + kq * 4 + rr;
        size_t obase = base + (size_t)tok * H_;
#pragma unroll
        for (int j2 = 0; j2 < 4; j2++) {
            int d = j2 * 16 + lr;
            xpre[obase + d] = hin[obase + d] + acc_o[j2][rr] * linv;
        }
    }
}

// ---------------------------------------------------------------------------
// LayerNorm over H=1280; one block per row. fp32 in, f16 out.
// ---------------------------------------------------------------------------
__global__ __launch_bounds__(256) void ln_kernel(const float* __restrict__ xpre,
                                                 const float* __restrict__ g,
                                                 const float* __restrict__ bb,
                                                 f16* __restrict__ xln) {
    int row = blockIdx.x, t = threadIdx.x;
    const float* xr = xpre + (size_t)row * H_;
    float xv[5], s1 = 0.f, s2 = 0.f;
#pragma unroll
    for (int i = 0; i < 5; i++) {
        float v = xr[t + 256 * i];
        xv[i] = v; s1 += v; s2 += v * v;
    }
#pragma unroll
    for (int o = 32; o >= 1; o >>= 1) { s1 += __shfl_xor(s1, o); s2 += __shfl_xor(s2, o); }
    __shared__ float r1[4], r2[4];
    int wv = t >> 6, lane = t & 63;
    if (lane == 0) { r1[wv] = s1; r2[wv] = s2; }
    __syncthreads();
    float m1 = (r1[0] + r1[1] + r1[2] + r1[3]) * (1.0f / H_);
    float m2 = (r2[0] + r2[1] + r2[2] + r2[3]) * (1.0f / H_);
    float rstd = rsqrtf(m2 - m1 * m1 + 1e-5f);
#pragma unroll
    for (int i = 0; i < 5; i++) {
        int c = t + 256 * i;
        float v = (xv[i] - m1) * rstd * g[c] + bb[c];
        xln[(size_t)row * H_ + c] = (f16)v;
    }
}

// ---------------------------------------------------------------------------
extern "C" void kernel_launch(void* const* d_in, const int* in_sizes, int n_in,
                              void* d_out, int out_size, void* d_ws, size_t ws_size,
                              hipStream_t stream) {
    (void)in_sizes; (void)n_in; (void)out_size; (void)ws_size;
    const float* hin  = (const float*)d_in[0];
    const float* mask = (const float*)d_in[1];
    const float* Wq = (const float*)d_in[2];  const float* bq = (const float*)d_in[3];
    const float* Wk = (const float*)d_in[4];  const float* bk = (const float*)d_in[5];
    const float* Wv = (const float*)d_in[6];  const float* bv = (const float*)d_in[7];
    const float* Wct1 = (const float*)d_in[8];  const float* bct1 = (const float*)d_in[9];
    const float* Wct2 = (const float*)d_in[10]; const float* bct2 = (const float*)d_in[11];
    const float* Mg = (const float*)d_in[12];   const float* bscale = (const float*)d_in[13];
    const float* Wptm = (const float*)d_in[14]; const float* bptm = (const float*)d_in[15];
    const float* lng = (const float*)d_in[16];  const float* lnb = (const float*)d_in[17];
    const float* Wf1 = (const float*)d_in[18];  const float* bf1 = (const float*)d_in[19];
    const float* Wf2 = (const float*)d_in[20];  const float* bf2 = (const float*)d_in[21];

    char* ws = (char*)d_ws;
    const size_t SZ_PT  = (size_t)B_ * S_ * P_ * 4;       // 131072
    const size_t SZ_H16 = (size_t)B_ * S_ * H_ * 2;       // 10485760 (f16)
    const size_t SZ_H32 = (size_t)B_ * S_ * H_ * 4;       // 20971520 (f32)
    const size_t SZ_WH  = (size_t)H_ * H_ * 2;            // 3276800
    const size_t SZ_WI  = (size_t)I_ * H_ * 2;            // 13107200
    float* ptm  = (float*)(ws + 256);
    float* tg   = (float*)(ws + 256 + SZ_PT);
    char* A0    = ws + 256 + 2 * SZ_PT;
    f16* hin16  = (f16*)(A0);
    f16* qkvb   = (f16*)(A0 + SZ_H16);         // fused [4096,3840] = 31.5 MB
    float* xpre = (float*)(A0 + 4 * SZ_H16);   // f32 (21 MB)
    f16* xln    = (f16*)(A0 + 4 * SZ_H16 + SZ_H32);
    f16* bbias  = (f16*)(A0 + 5 * SZ_H16 + SZ_H32);       // 8.39 MB
    char* WA    = A0 + 5 * SZ_H16 + SZ_H32 + (size_t)B_ * S_ * S_ * 2;
    f16* Wq16   = (f16*)(WA);                  // [Wq;Wk;Wv] fused [3840,1280]
    f16* Wk16   = (f16*)(WA + SZ_WH);
    f16* Wv16   = (f16*)(WA + 2 * SZ_WH);
    f16* Wf116  = (f16*)(WA + 3 * SZ_WH);
    f16* Wf216  = (f16*)(WA + 3 * SZ_WH + SZ_WI);
    f16* g1     = (f16*)(A0);                  // aliases hin16+qkvb (dead by FFN1)
    float* pbuf = (float*)(WA + 3 * SZ_WH + 2 * SZ_WI);   // 2 x 21.0 MB f32 partials
    // 3rd split-K partial aliases xpre (f32, dead after ln_kernel)

    // prep: 1024 ptm blocks + 17600 cvt blocks (3x1600 + 2x6400) fused.
    prep_kernel<<<1024 + 17600, 256, 0, stream>>>(
        hin, Wptm, bptm, Mg, Wct1, bct1, Wct2, bct2, ptm, tg, hin16,
        Wq, Wk, Wv, Wf1, Wf2, Wq16, Wk16, Wv16, Wf116, Wf216);
    bias_kernel<<<B_ * S_, 256, 0, stream>>>(tg, ptm, mask, bscale, bbias);
    // Fused QKV: deep-pipelined 256^2, 16 x 15 = 240 blocks (one CU round).
    gemm256_qkv<<<dim3(16, 15), 512, 0, stream>>>(hin16, Wq16, bq, bk, bv, qkvb);
    attn_kernel<<<dim3(S_ / 64, NH_, B_), 256, 0, stream>>>(qkvb, bbias, hin, xpre);
    ln_kernel<<<B_ * S_, 256, 0, stream>>>(xpre, lng, lnb, xln);
    // FFN1: m97 128^2 (2 blocks/CU; measured 77-78 us vs 81.4 for 256x320).
    gemm128<1, f16><<<dim3(32, I_ / 128), 256, 0, stream>>>(xln, Wf116, bf1, g1, I_, H_);
    // FFN2 deep-pipelined 256^2 split-K=3, f32 partials: 240 blocks (1 round)
    gemm256_sk<<<dim3(16, H_ / 256, 3), 512, 0, stream>>>(
        g1, Wf216, pbuf, pbuf + (size_t)B_ * S_ * H_, xpre, H_, I_);
    reduce3_kernel<<<(B_ * S_ * H_) / 4 / 256, 256, 0, stream>>>(
        pbuf, pbuf + (size_t)B_ * S_ * H_, xpre, bf2, xln, (float*)d_out);
}